// Round 13
// baseline (462.295 us; speedup 1.0000x reference)
//
#include <hip/hip_runtime.h>

// Problem constants
#define BATCH   4
#define SEQ     2048
#define DMODEL  1024
#define NHEADS  16
#define HDIM    64
// SCALE * log2(e) folded into Q at the GEMM epilogue: exp(s*0.125) = exp2(s*QSC)
#define QSC     0.18033688f

typedef short s16x8 __attribute__((ext_vector_type(8)));
typedef float f32x4 __attribute__((ext_vector_type(4)));
typedef const __attribute__((address_space(1))) unsigned int* gas_t;
typedef __attribute__((address_space(3))) unsigned int* las_t;

__device__ inline unsigned short f2bf(float f) {
    unsigned int u = __float_as_uint(f);
    u += 0x7FFF + ((u >> 16) & 1);   // RNE
    return (unsigned short)(u >> 16);
}

__device__ __forceinline__ float exp2_fast(float x) {
#if __has_builtin(__builtin_amdgcn_exp2f)
    return __builtin_amdgcn_exp2f(x);
#else
    return exp2f(x);
#endif
}

__device__ __forceinline__ float rcp_fast(float x) {
#if __has_builtin(__builtin_amdgcn_rcpf)
    return __builtin_amdgcn_rcpf(x);
#else
    return 1.0f / x;
#endif
}

// pack two positive floats to bf16x2 (round-half-up), lo in low 16 bits
__device__ __forceinline__ unsigned int pack_bf16x2(float lo, float hi) {
    unsigned int a = __float_as_uint(lo) + 0x8000u;
    unsigned int b = __float_as_uint(hi) + 0x8000u;
#if __has_builtin(__builtin_amdgcn_perm)
    return __builtin_amdgcn_perm(b, a, 0x07060302u);
#else
    return (a >> 16) | (b & 0xFFFF0000u);
#endif
}

// ---------------- fp32 -> bf16 convert (4 elems/thread), both tensors ------
// R8-proven: merged into one dispatch.
__global__ void cvt_bf16_2(const float* __restrict__ a,
                           unsigned short* __restrict__ oa, int n4a,
                           const float* __restrict__ bsrc,
                           unsigned short* __restrict__ ob, int n4b) {
    int i = blockIdx.x * blockDim.x + threadIdx.x;
    if (i < n4a) {
        float4 v = ((const float4*)a)[i];
        ushort4 o;
        o.x = f2bf(v.x); o.y = f2bf(v.y); o.z = f2bf(v.z); o.w = f2bf(v.w);
        ((ushort4*)oa)[i] = o;
    } else {
        int j = i - n4a;
        if (j < n4b) {
            float4 v = ((const float4*)bsrc)[j];
            ushort4 o;
            o.x = f2bf(v.x); o.y = f2bf(v.y); o.z = f2bf(v.z); o.w = f2bf(v.w);
            ((ushort4*)ob)[j] = o;
        }
    }
}

// ---------------- QKV projection GEMM ----------------
// R8-proven 2-phase: global_load_lds staging + XCD swizzle + dbuf +
// chunk-XOR bank swizzle. Untouched.
__global__ __launch_bounds__(256) void qkv_gemm(
    const unsigned short* __restrict__ Xb,
    const unsigned short* __restrict__ Wb,
    unsigned short* __restrict__ Qo,
    unsigned short* __restrict__ Ko,
    unsigned short* __restrict__ Vt)
{
    __shared__ __align__(16) unsigned short As[2 * 128 * 32];
    __shared__ __align__(16) unsigned short Bs[2 * 128 * 32];

    const int t    = threadIdx.x;
    // XCD swizzle: flat in dispatch order (x fastest), 8 XCDs round-robin
    const int flat = blockIdx.y * 24 + blockIdx.x;
    const int sw   = (flat & 7) * 192 + (flat >> 3);
    const int m0   = (sw / 24) * 128;
    const int n0   = (sw % 24) * 128;

    const int wid  = t >> 6;
    const int lane = t & 63;
    const int l15  = lane & 15;
    const int quad = lane >> 4;
    const int wm   = (wid >> 1) * 64;
    const int wn   = (wid & 1) * 64;

    const int rA   = wid * 32 + (lane >> 2);
    const int kcol_phys = (lane & 3) * 8;
    const int kcol_src  = ((lane & 3) ^ ((rA >> 1) & 3)) * 8;
    const unsigned short* gA = &Xb[(size_t)(m0 + rA) * 1024 + kcol_src];
    const unsigned short* gB = &Wb[(size_t)(n0 + rA) * 1024 + kcol_src];

    const int cswq = (quad ^ ((l15 >> 1) & 3)) * 8;

    f32x4 acc[4][4] = {};

    auto stage = [&](int k0, int bufE) {
        #pragma unroll
        for (int rd = 0; rd < 2; rd++) {
            __builtin_amdgcn_global_load_lds(
                (gas_t)(const void*)(gA + rd * 16 * 1024 + k0),
                (las_t)(void*)&As[bufE + (rA + rd * 16) * 32 + kcol_phys], 16, 0, 0);
            __builtin_amdgcn_global_load_lds(
                (gas_t)(const void*)(gB + rd * 16 * 1024 + k0),
                (las_t)(void*)&Bs[bufE + (rA + rd * 16) * 32 + kcol_phys], 16, 0, 0);
        }
    };

    auto comp = [&](int bufE) {
        s16x8 af[4], bf[4];
        #pragma unroll
        for (int mt = 0; mt < 4; mt++)
            af[mt] = *(const s16x8*)&As[bufE + (wm + mt * 16 + l15) * 32 + cswq];
        #pragma unroll
        for (int nt = 0; nt < 4; nt++)
            bf[nt] = *(const s16x8*)&Bs[bufE + (wn + nt * 16 + l15) * 32 + cswq];
        #pragma unroll
        for (int mt = 0; mt < 4; mt++)
            #pragma unroll
            for (int nt = 0; nt < 4; nt++)
                acc[mt][nt] = __builtin_amdgcn_mfma_f32_16x16x32_bf16(
                    af[mt], bf[nt], acc[mt][nt], 0, 0, 0);
    };

    // prologue
    stage(0, 0);
    __syncthreads();

    #pragma unroll 1
    for (int k0 = 0; k0 < 1024; k0 += 64) {
        stage(k0 + 32, 4096);
        comp(0);
        __syncthreads();
        if (k0 + 64 < 1024) stage(k0 + 64, 0);
        comp(4096);
        __syncthreads();
    }

    #pragma unroll
    for (int mt = 0; mt < 4; mt++) {
        const int mbase = m0 + wm + mt * 16 + quad * 4;
        const int b     = mbase >> 11;
        const int nbase = mbase & 2047;
        #pragma unroll
        for (int nt = 0; nt < 4; nt++) {
            const int o  = n0 + wn + nt * 16 + l15;
            const int p  = o >> 10;
            const int oo = o & 1023;
            const int h  = oo >> 6;
            const int d  = oo & 63;
            if (p == 0) {
                #pragma unroll
                for (int r = 0; r < 4; r++)
                    Qo[((size_t)(b * 16 + h) * 2048 + nbase + r) * 64 + d] =
                        f2bf(acc[mt][nt][r] * QSC);
            } else if (p == 1) {
                #pragma unroll
                for (int r = 0; r < 4; r++)
                    Ko[((size_t)(b * 16 + h) * 2048 + nbase + r) * 64 + d] =
                        f2bf(acc[mt][nt][r]);
            } else {
                ushort4 v4;
                v4.x = f2bf(acc[mt][nt][0]);
                v4.y = f2bf(acc[mt][nt][1]);
                v4.z = f2bf(acc[mt][nt][2]);
                v4.w = f2bf(acc[mt][nt][3]);
                *(ushort4*)&Vt[((size_t)(b * 16 + h) * 64 + d) * 2048 + nbase] = v4;
            }
        }
    }
}

// ---------------- fused attention ----------------
// R13: 8-wave blocks (R12-proven) + V direct from global, done RIGHT this
// time. R10's regression mechanism: vmcnt is in-order; vb loads issued
// AFTER the staging DMA forced the DMA to drain at the PV wait. Fix: issue
// vb(kt+1) BEFORE stageK(kt+1) each iteration (double-buffered vb regs) —
// the compiler's vb wait is then vmcnt(N>0), K-DMA stays in flight, and V
// latency hides under a full tile of compute. V addressing = R10-verified.
// Removes V from LDS: 69.6 -> 52 KB, LDS traffic -33%, staging DMA halved.
// V comes from L2 (~12 TB/s demand vs 34.5 ceiling).
// LDS map (ushort elems): K0@0, K1@4096, P@8192+w*2304.
#define PSTRIDE 72
#define PBASE   8192

__global__ __launch_bounds__(512, 4) void attn(
    const unsigned short* __restrict__ Q,
    const unsigned short* __restrict__ K,
    const unsigned short* __restrict__ Vt,
    float* __restrict__ out)
{
    __shared__ __align__(16) unsigned short LDS[PBASE + 8 * 32 * PSTRIDE];

    const int t    = threadIdx.x;
    const int w    = t >> 6;                // 0..7
    const int lane = t & 63;
    const int l15  = lane & 15;
    const int quad = lane >> 4;
    const int head = blockIdx.y;            // b*16 + h
    const int b    = head >> 4;
    const int h    = head & 15;
    const int q0   = blockIdx.x * 256 + w * 32;

    const unsigned short* Qh = Q  + (size_t)head * 2048 * 64;
    const unsigned short* Kh = K  + (size_t)head * 2048 * 64;
    const unsigned short* Vh = Vt + (size_t)head * 64 * 2048;

    // ---- K staging (per thread, lane-linear LDS dst); 512 threads cover
    // the full 8KB tile in ONE DMA instruction.
    // phys chunk i = t holds logical (row=i>>3, col=(i&7)^(row&7))
    const int r0 = t >> 3;                    // 0..63
    const int c0 = (t & 7) ^ (r0 & 7);
    const unsigned short* srcK = Kh + r0 * 64 + c0 * 8;

    auto stageK = [&](int kt, int bufE) {
        __builtin_amdgcn_global_load_lds(
            (gas_t)(const void*)(srcK + kt * 4096),
            (las_t)(void*)&LDS[bufE + t * 8], 16, 0, 0);
    };

    // V direct-read base (R10-verified): V^T row d = dt*16+l15,
    // col n = kt*64 + kc*32 + quad*8
    const unsigned short* vbase = Vh + (size_t)l15 * 2048 + quad * 8;
    auto loadV = [&](int kt, s16x8 (&vb)[4][2]) {
        #pragma unroll
        for (int dt = 0; dt < 4; dt++)
            #pragma unroll
            for (int kc = 0; kc < 2; kc++)
                vb[dt][kc] = *(const s16x8*)&vbase[(size_t)dt * 16 * 2048 + kt * 64 + kc * 32];
    };

    // Q fragments (pre-scaled by QSC in gemm), B-operand role
    s16x8 qb[2][2];
    #pragma unroll
    for (int mt = 0; mt < 2; mt++)
        #pragma unroll
        for (int kc = 0; kc < 2; kc++)
            qb[mt][kc] = *(const s16x8*)&Qh[(size_t)(q0 + mt * 16 + l15) * 64 + kc * 32 + quad * 8];

    // ones B-fragment (bf16 1.0) for MFMA row-sums
    s16x8 onesf;
    #pragma unroll
    for (int i = 0; i < 8; i++) onesf[i] = (short)0x3F80;
    const f32x4 fz = {0.f, 0.f, 0.f, 0.f};

    f32x4 y[2][4] = {};
    f32x4 ysum[2] = {};
    unsigned short* P = &LDS[PBASE + w * (32 * PSTRIDE)];

    // swizzled in-tile column offsets (elems) for K LDS reads
    const int x7   = l15 & 7;
    const int csw0 = (quad ^ x7) * 8;
    const int csw1 = ((4 + quad) ^ x7) * 8;

    auto compute = [&](int bufE, s16x8 (&vb)[4][2]) {
        // K fragments from LDS
        s16x8 kb[4][2];
        #pragma unroll
        for (int nt = 0; nt < 4; nt++) {
            const int rowb = bufE + (nt * 16 + l15) * 64;
            kb[nt][0] = *(const s16x8*)&LDS[rowb + csw0];
            kb[nt][1] = *(const s16x8*)&LDS[rowb + csw1];
        }
        // S^T = K * Q^T  (kc=0 consumes shared zero C; kc=1 accumulates)
        f32x4 st[4][2];
        #pragma unroll
        for (int nt = 0; nt < 4; nt++)
            #pragma unroll
            for (int mt = 0; mt < 2; mt++)
                st[nt][mt] = __builtin_amdgcn_mfma_f32_16x16x32_bf16(
                    kb[nt][0], qb[mt][0], fz, 0, 0, 0);
        #pragma unroll
        for (int nt = 0; nt < 4; nt++)
            #pragma unroll
            for (int mt = 0; mt < 2; mt++)
                st[nt][mt] = __builtin_amdgcn_mfma_f32_16x16x32_bf16(
                    kb[nt][1], qb[mt][1], st[nt][mt], 0, 0, 0);
        // exp2 + pack + ds_write_b64 into per-wave P region
        #pragma unroll
        for (int mt = 0; mt < 2; mt++)
            #pragma unroll
            for (int nt = 0; nt < 4; nt++) {
                float p0 = exp2_fast(st[nt][mt][0]);
                float p1 = exp2_fast(st[nt][mt][1]);
                float p2 = exp2_fast(st[nt][mt][2]);
                float p3 = exp2_fast(st[nt][mt][3]);
                uint2 u;
                u.x = pack_bf16x2(p0, p1);
                u.y = pack_bf16x2(p2, p3);
                *(uint2*)&P[(mt * 16 + l15) * PSTRIDE + nt * 16 + quad * 4] = u;
            }
        // Y += P V ; row sums via ones-MFMA
        #pragma unroll
        for (int kc = 0; kc < 2; kc++) {
            s16x8 pa[2];
            #pragma unroll
            for (int mt = 0; mt < 2; mt++)
                pa[mt] = *(const s16x8*)&P[(mt * 16 + l15) * PSTRIDE + kc * 32 + quad * 8];
            #pragma unroll
            for (int mt = 0; mt < 2; mt++)
                ysum[mt] = __builtin_amdgcn_mfma_f32_16x16x32_bf16(
                    pa[mt], onesf, ysum[mt], 0, 0, 0);
            #pragma unroll
            for (int mt = 0; mt < 2; mt++)
                #pragma unroll
                for (int dt = 0; dt < 4; dt++)
                    y[mt][dt] = __builtin_amdgcn_mfma_f32_16x16x32_bf16(
                        pa[mt], vb[dt][kc], y[mt][dt], 0, 0, 0);
        }
    };

    // -------- prologue --------
    s16x8 vbA[4][2], vbB[4][2];
    stageK(0, 0);
    loadV(0, vbA);
    __syncthreads();            // drain + barrier: K0 ready (vbA also lands)

    // -------- main loop: vb(next) BEFORE stageK(next) so the vb wait
    // leaves the K-DMA in flight; barrier per half-iter as before ----
    #pragma unroll 1
    for (int kt = 0; kt < 32; kt += 2) {
        loadV(kt + 1, vbB);
        stageK(kt + 1, 4096);           // kt+1 <= 31 always
        compute(0, vbA);
        __syncthreads();
        if (kt + 2 < 32) {
            loadV(kt + 2, vbA);
            stageK(kt + 2, 0);
        }
        compute(4096, vbB);
        __syncthreads();
    }

    // ysum[mt][r] holds the full row sum for q-row = mt*16 + quad*4 + r
    float rinv[2][4];
    #pragma unroll
    for (int mt = 0; mt < 2; mt++)
        #pragma unroll
        for (int r = 0; r < 4; r++)
            rinv[mt][r] = rcp_fast(ysum[mt][r]);

    // out[b, n, h*64+d] fp32; C-layout: col=l15 -> d, row=quad*4+r -> m
    #pragma unroll
    for (int mt = 0; mt < 2; mt++)
        #pragma unroll
        for (int dt = 0; dt < 4; dt++)
            #pragma unroll
            for (int r = 0; r < 4; r++) {
                const int n = q0 + mt * 16 + quad * 4 + r;
                const int d = dt * 16 + l15;
                out[((size_t)(b * 2048 + n)) * 1024 + h * 64 + d] =
                    y[mt][dt][r] * rinv[mt][r];
            }
}

// ---------------- launch ----------------
extern "C" void kernel_launch(void* const* d_in, const int* in_sizes, int n_in,
                              void* d_out, int out_size, void* d_ws, size_t ws_size,
                              hipStream_t stream) {
    const float* X = (const float*)d_in[0];   // [4,2048,1024]
    const float* W = (const float*)d_in[1];   // [3072,1024]
    float* out = (float*)d_out;

    char* ws = (char*)d_ws;
    unsigned short* Xb = (unsigned short*)(ws);                 // 16.8 MB
    unsigned short* Wb = (unsigned short*)(ws + 16777216);      //  6.3 MB
    unsigned short* Qb = (unsigned short*)(ws + 23068672);      // 16.8 MB
    unsigned short* Kb = (unsigned short*)(ws + 39845888);      // 16.8 MB
    unsigned short* Vt = (unsigned short*)(ws + 56623104);      // 16.8 MB (ends 73.4 MB)

    cvt_bf16_2<<<dim3(11264), dim3(256), 0, stream>>>(X, Xb, 2097152, W, Wb, 786432);
    qkv_gemm<<<dim3(24, 64), dim3(256), 0, stream>>>(Xb, Wb, Qb, Kb, Vt);
    attn<<<dim3(8, 64), dim3(512), 0, stream>>>(Qb, Kb, Vt, out);
}

// Round 14
// 329.232 us; speedup vs baseline: 1.4042x; 1.4042x over previous
//
#include <hip/hip_runtime.h>

// Problem constants
#define BATCH   4
#define SEQ     2048
#define DMODEL  1024
#define NHEADS  16
#define HDIM    64
// SCALE * log2(e) folded into Q at the GEMM epilogue: exp(s*0.125) = exp2(s*QSC)
#define QSC     0.18033688f

typedef short s16x8 __attribute__((ext_vector_type(8)));
typedef float f32x4 __attribute__((ext_vector_type(4)));
typedef const __attribute__((address_space(1))) unsigned int* gas_t;
typedef __attribute__((address_space(3))) unsigned int* las_t;

__device__ inline unsigned short f2bf(float f) {
    unsigned int u = __float_as_uint(f);
    u += 0x7FFF + ((u >> 16) & 1);   // RNE
    return (unsigned short)(u >> 16);
}

__device__ __forceinline__ float exp2_fast(float x) {
#if __has_builtin(__builtin_amdgcn_exp2f)
    return __builtin_amdgcn_exp2f(x);
#else
    return exp2f(x);
#endif
}

__device__ __forceinline__ float rcp_fast(float x) {
#if __has_builtin(__builtin_amdgcn_rcpf)
    return __builtin_amdgcn_rcpf(x);
#else
    return 1.0f / x;
#endif
}

// pack two positive floats to bf16x2 (round-half-up), lo in low 16 bits
__device__ __forceinline__ unsigned int pack_bf16x2(float lo, float hi) {
    unsigned int a = __float_as_uint(lo) + 0x8000u;
    unsigned int b = __float_as_uint(hi) + 0x8000u;
#if __has_builtin(__builtin_amdgcn_perm)
    return __builtin_amdgcn_perm(b, a, 0x07060302u);
#else
    return (a >> 16) | (b & 0xFFFF0000u);
#endif
}

// ---------------- fp32 -> bf16 convert (4 elems/thread), both tensors ------
// R8-proven: merged into one dispatch.
__global__ void cvt_bf16_2(const float* __restrict__ a,
                           unsigned short* __restrict__ oa, int n4a,
                           const float* __restrict__ bsrc,
                           unsigned short* __restrict__ ob, int n4b) {
    int i = blockIdx.x * blockDim.x + threadIdx.x;
    if (i < n4a) {
        float4 v = ((const float4*)a)[i];
        ushort4 o;
        o.x = f2bf(v.x); o.y = f2bf(v.y); o.z = f2bf(v.z); o.w = f2bf(v.w);
        ((ushort4*)oa)[i] = o;
    } else {
        int j = i - n4a;
        if (j < n4b) {
            float4 v = ((const float4*)bsrc)[j];
            ushort4 o;
            o.x = f2bf(v.x); o.y = f2bf(v.y); o.z = f2bf(v.z); o.w = f2bf(v.w);
            ((ushort4*)ob)[j] = o;
        }
    }
}

// ---------------- QKV projection GEMM ----------------
// R8-proven 2-phase: global_load_lds staging + XCD swizzle + dbuf +
// chunk-XOR bank swizzle. Untouched.
__global__ __launch_bounds__(256) void qkv_gemm(
    const unsigned short* __restrict__ Xb,
    const unsigned short* __restrict__ Wb,
    unsigned short* __restrict__ Qo,
    unsigned short* __restrict__ Ko,
    unsigned short* __restrict__ Vt)
{
    __shared__ __align__(16) unsigned short As[2 * 128 * 32];
    __shared__ __align__(16) unsigned short Bs[2 * 128 * 32];

    const int t    = threadIdx.x;
    // XCD swizzle: flat in dispatch order (x fastest), 8 XCDs round-robin
    const int flat = blockIdx.y * 24 + blockIdx.x;
    const int sw   = (flat & 7) * 192 + (flat >> 3);
    const int m0   = (sw / 24) * 128;
    const int n0   = (sw % 24) * 128;

    const int wid  = t >> 6;
    const int lane = t & 63;
    const int l15  = lane & 15;
    const int quad = lane >> 4;
    const int wm   = (wid >> 1) * 64;
    const int wn   = (wid & 1) * 64;

    const int rA   = wid * 32 + (lane >> 2);
    const int kcol_phys = (lane & 3) * 8;
    const int kcol_src  = ((lane & 3) ^ ((rA >> 1) & 3)) * 8;
    const unsigned short* gA = &Xb[(size_t)(m0 + rA) * 1024 + kcol_src];
    const unsigned short* gB = &Wb[(size_t)(n0 + rA) * 1024 + kcol_src];

    const int cswq = (quad ^ ((l15 >> 1) & 3)) * 8;

    f32x4 acc[4][4] = {};

    auto stage = [&](int k0, int bufE) {
        #pragma unroll
        for (int rd = 0; rd < 2; rd++) {
            __builtin_amdgcn_global_load_lds(
                (gas_t)(const void*)(gA + rd * 16 * 1024 + k0),
                (las_t)(void*)&As[bufE + (rA + rd * 16) * 32 + kcol_phys], 16, 0, 0);
            __builtin_amdgcn_global_load_lds(
                (gas_t)(const void*)(gB + rd * 16 * 1024 + k0),
                (las_t)(void*)&Bs[bufE + (rA + rd * 16) * 32 + kcol_phys], 16, 0, 0);
        }
    };

    auto comp = [&](int bufE) {
        s16x8 af[4], bf[4];
        #pragma unroll
        for (int mt = 0; mt < 4; mt++)
            af[mt] = *(const s16x8*)&As[bufE + (wm + mt * 16 + l15) * 32 + cswq];
        #pragma unroll
        for (int nt = 0; nt < 4; nt++)
            bf[nt] = *(const s16x8*)&Bs[bufE + (wn + nt * 16 + l15) * 32 + cswq];
        #pragma unroll
        for (int mt = 0; mt < 4; mt++)
            #pragma unroll
            for (int nt = 0; nt < 4; nt++)
                acc[mt][nt] = __builtin_amdgcn_mfma_f32_16x16x32_bf16(
                    af[mt], bf[nt], acc[mt][nt], 0, 0, 0);
    };

    // prologue
    stage(0, 0);
    __syncthreads();

    #pragma unroll 1
    for (int k0 = 0; k0 < 1024; k0 += 64) {
        stage(k0 + 32, 4096);
        comp(0);
        __syncthreads();
        if (k0 + 64 < 1024) stage(k0 + 64, 0);
        comp(4096);
        __syncthreads();
    }

    #pragma unroll
    for (int mt = 0; mt < 4; mt++) {
        const int mbase = m0 + wm + mt * 16 + quad * 4;
        const int b     = mbase >> 11;
        const int nbase = mbase & 2047;
        #pragma unroll
        for (int nt = 0; nt < 4; nt++) {
            const int o  = n0 + wn + nt * 16 + l15;
            const int p  = o >> 10;
            const int oo = o & 1023;
            const int h  = oo >> 6;
            const int d  = oo & 63;
            if (p == 0) {
                #pragma unroll
                for (int r = 0; r < 4; r++)
                    Qo[((size_t)(b * 16 + h) * 2048 + nbase + r) * 64 + d] =
                        f2bf(acc[mt][nt][r] * QSC);
            } else if (p == 1) {
                #pragma unroll
                for (int r = 0; r < 4; r++)
                    Ko[((size_t)(b * 16 + h) * 2048 + nbase + r) * 64 + d] =
                        f2bf(acc[mt][nt][r]);
            } else {
                ushort4 v4;
                v4.x = f2bf(acc[mt][nt][0]);
                v4.y = f2bf(acc[mt][nt][1]);
                v4.z = f2bf(acc[mt][nt][2]);
                v4.w = f2bf(acc[mt][nt][3]);
                *(ushort4*)&Vt[((size_t)(b * 16 + h) * 64 + d) * 2048 + nbase] = v4;
            }
        }
    }
}

// ---------------- fused attention ----------------
// R14 = R13 with the launch-bounds bug fixed. R13's 3.3x regression was
// fully explained by __launch_bounds__(512,4) forcing VGPR=64 (the 2nd arg
// behaved as min-BLOCKS/CU: 4x8=32 waves/CU) -> vbA/vbB spilled to scratch
// (WRITE_SIZE 712MB). Plain __launch_bounds__(512) lets the allocator pick
// ~112-128 VGPR (R12 chose 84 for the same structure minus vb), keeping
// 2 blocks/CU. V-pipeline logic unchanged: vb(next) issued BEFORE
// stageK(next) so the vb wait leaves the K-DMA in flight (vmcnt in-order).
// No-spill canary: WRITE_SIZE ~32KB. If VGPR>128 -> revert to R12.
// LDS map (ushort elems): K0@0, K1@4096, P@8192+w*2304.
#define PSTRIDE 72
#define PBASE   8192

__global__ __launch_bounds__(512) void attn(
    const unsigned short* __restrict__ Q,
    const unsigned short* __restrict__ K,
    const unsigned short* __restrict__ Vt,
    float* __restrict__ out)
{
    __shared__ __align__(16) unsigned short LDS[PBASE + 8 * 32 * PSTRIDE];

    const int t    = threadIdx.x;
    const int w    = t >> 6;                // 0..7
    const int lane = t & 63;
    const int l15  = lane & 15;
    const int quad = lane >> 4;
    const int head = blockIdx.y;            // b*16 + h
    const int b    = head >> 4;
    const int h    = head & 15;
    const int q0   = blockIdx.x * 256 + w * 32;

    const unsigned short* Qh = Q  + (size_t)head * 2048 * 64;
    const unsigned short* Kh = K  + (size_t)head * 2048 * 64;
    const unsigned short* Vh = Vt + (size_t)head * 64 * 2048;

    // ---- K staging (per thread, lane-linear LDS dst); 512 threads cover
    // the full 8KB tile in ONE DMA instruction.
    // phys chunk i = t holds logical (row=i>>3, col=(i&7)^(row&7))
    const int r0 = t >> 3;                    // 0..63
    const int c0 = (t & 7) ^ (r0 & 7);
    const unsigned short* srcK = Kh + r0 * 64 + c0 * 8;

    auto stageK = [&](int kt, int bufE) {
        __builtin_amdgcn_global_load_lds(
            (gas_t)(const void*)(srcK + kt * 4096),
            (las_t)(void*)&LDS[bufE + t * 8], 16, 0, 0);
    };

    // V direct-read base (R10-verified): V^T row d = dt*16+l15,
    // col n = kt*64 + kc*32 + quad*8
    const unsigned short* vbase = Vh + (size_t)l15 * 2048 + quad * 8;
    auto loadV = [&](int kt, s16x8 (&vb)[4][2]) {
        #pragma unroll
        for (int dt = 0; dt < 4; dt++)
            #pragma unroll
            for (int kc = 0; kc < 2; kc++)
                vb[dt][kc] = *(const s16x8*)&vbase[(size_t)dt * 16 * 2048 + kt * 64 + kc * 32];
    };

    // Q fragments (pre-scaled by QSC in gemm), B-operand role
    s16x8 qb[2][2];
    #pragma unroll
    for (int mt = 0; mt < 2; mt++)
        #pragma unroll
        for (int kc = 0; kc < 2; kc++)
            qb[mt][kc] = *(const s16x8*)&Qh[(size_t)(q0 + mt * 16 + l15) * 64 + kc * 32 + quad * 8];

    // ones B-fragment (bf16 1.0) for MFMA row-sums
    s16x8 onesf;
    #pragma unroll
    for (int i = 0; i < 8; i++) onesf[i] = (short)0x3F80;
    const f32x4 fz = {0.f, 0.f, 0.f, 0.f};

    f32x4 y[2][4] = {};
    f32x4 ysum[2] = {};
    unsigned short* P = &LDS[PBASE + w * (32 * PSTRIDE)];

    // swizzled in-tile column offsets (elems) for K LDS reads
    const int x7   = l15 & 7;
    const int csw0 = (quad ^ x7) * 8;
    const int csw1 = ((4 + quad) ^ x7) * 8;

    auto compute = [&](int bufE, s16x8 (&vb)[4][2]) {
        // K fragments from LDS
        s16x8 kb[4][2];
        #pragma unroll
        for (int nt = 0; nt < 4; nt++) {
            const int rowb = bufE + (nt * 16 + l15) * 64;
            kb[nt][0] = *(const s16x8*)&LDS[rowb + csw0];
            kb[nt][1] = *(const s16x8*)&LDS[rowb + csw1];
        }
        // S^T = K * Q^T  (kc=0 consumes shared zero C; kc=1 accumulates)
        f32x4 st[4][2];
        #pragma unroll
        for (int nt = 0; nt < 4; nt++)
            #pragma unroll
            for (int mt = 0; mt < 2; mt++)
                st[nt][mt] = __builtin_amdgcn_mfma_f32_16x16x32_bf16(
                    kb[nt][0], qb[mt][0], fz, 0, 0, 0);
        #pragma unroll
        for (int nt = 0; nt < 4; nt++)
            #pragma unroll
            for (int mt = 0; mt < 2; mt++)
                st[nt][mt] = __builtin_amdgcn_mfma_f32_16x16x32_bf16(
                    kb[nt][1], qb[mt][1], st[nt][mt], 0, 0, 0);
        // exp2 + pack + ds_write_b64 into per-wave P region
        #pragma unroll
        for (int mt = 0; mt < 2; mt++)
            #pragma unroll
            for (int nt = 0; nt < 4; nt++) {
                float p0 = exp2_fast(st[nt][mt][0]);
                float p1 = exp2_fast(st[nt][mt][1]);
                float p2 = exp2_fast(st[nt][mt][2]);
                float p3 = exp2_fast(st[nt][mt][3]);
                uint2 u;
                u.x = pack_bf16x2(p0, p1);
                u.y = pack_bf16x2(p2, p3);
                *(uint2*)&P[(mt * 16 + l15) * PSTRIDE + nt * 16 + quad * 4] = u;
            }
        // Y += P V ; row sums via ones-MFMA
        #pragma unroll
        for (int kc = 0; kc < 2; kc++) {
            s16x8 pa[2];
            #pragma unroll
            for (int mt = 0; mt < 2; mt++)
                pa[mt] = *(const s16x8*)&P[(mt * 16 + l15) * PSTRIDE + kc * 32 + quad * 8];
            #pragma unroll
            for (int mt = 0; mt < 2; mt++)
                ysum[mt] = __builtin_amdgcn_mfma_f32_16x16x32_bf16(
                    pa[mt], onesf, ysum[mt], 0, 0, 0);
            #pragma unroll
            for (int mt = 0; mt < 2; mt++)
                #pragma unroll
                for (int dt = 0; dt < 4; dt++)
                    y[mt][dt] = __builtin_amdgcn_mfma_f32_16x16x32_bf16(
                        pa[mt], vb[dt][kc], y[mt][dt], 0, 0, 0);
        }
    };

    // -------- prologue --------
    s16x8 vbA[4][2], vbB[4][2];
    stageK(0, 0);
    loadV(0, vbA);
    __syncthreads();            // drain + barrier: K0 ready (vbA also lands)

    // -------- main loop: vb(next) BEFORE stageK(next) so the vb wait
    // leaves the K-DMA in flight; barrier per half-iter as before ----
    #pragma unroll 1
    for (int kt = 0; kt < 32; kt += 2) {
        loadV(kt + 1, vbB);
        stageK(kt + 1, 4096);           // kt+1 <= 31 always
        compute(0, vbA);
        __syncthreads();
        if (kt + 2 < 32) {
            loadV(kt + 2, vbA);
            stageK(kt + 2, 0);
        }
        compute(4096, vbB);
        __syncthreads();
    }

    // ysum[mt][r] holds the full row sum for q-row = mt*16 + quad*4 + r
    float rinv[2][4];
    #pragma unroll
    for (int mt = 0; mt < 2; mt++)
        #pragma unroll
        for (int r = 0; r < 4; r++)
            rinv[mt][r] = rcp_fast(ysum[mt][r]);

    // out[b, n, h*64+d] fp32; C-layout: col=l15 -> d, row=quad*4+r -> m
    #pragma unroll
    for (int mt = 0; mt < 2; mt++)
        #pragma unroll
        for (int dt = 0; dt < 4; dt++)
            #pragma unroll
            for (int r = 0; r < 4; r++) {
                const int n = q0 + mt * 16 + quad * 4 + r;
                const int d = dt * 16 + l15;
                out[((size_t)(b * 2048 + n)) * 1024 + h * 64 + d] =
                    y[mt][dt][r] * rinv[mt][r];
            }
}

// ---------------- launch ----------------
extern "C" void kernel_launch(void* const* d_in, const int* in_sizes, int n_in,
                              void* d_out, int out_size, void* d_ws, size_t ws_size,
                              hipStream_t stream) {
    const float* X = (const float*)d_in[0];   // [4,2048,1024]
    const float* W = (const float*)d_in[1];   // [3072,1024]
    float* out = (float*)d_out;

    char* ws = (char*)d_ws;
    unsigned short* Xb = (unsigned short*)(ws);                 // 16.8 MB
    unsigned short* Wb = (unsigned short*)(ws + 16777216);      //  6.3 MB
    unsigned short* Qb = (unsigned short*)(ws + 23068672);      // 16.8 MB
    unsigned short* Kb = (unsigned short*)(ws + 39845888);      // 16.8 MB
    unsigned short* Vt = (unsigned short*)(ws + 56623104);      // 16.8 MB (ends 73.4 MB)

    cvt_bf16_2<<<dim3(11264), dim3(256), 0, stream>>>(X, Xb, 2097152, W, Wb, 786432);
    qkv_gemm<<<dim3(24, 64), dim3(256), 0, stream>>>(Xb, Wb, Qb, Kb, Vt);
    attn<<<dim3(8, 64), dim3(512), 0, stream>>>(Qb, Kb, Vt, out);
}

// Round 15
// 243.022 us; speedup vs baseline: 1.9023x; 1.3547x over previous
//
#include <hip/hip_runtime.h>

// Problem constants
#define BATCH   4
#define SEQ     2048
#define DMODEL  1024
#define NHEADS  16
#define HDIM    64
// SCALE * log2(e) folded into Q at the GEMM epilogue: exp(s*0.125) = exp2(s*QSC)
#define QSC     0.18033688f

typedef short s16x8 __attribute__((ext_vector_type(8)));
typedef float f32x4 __attribute__((ext_vector_type(4)));
typedef const __attribute__((address_space(1))) unsigned int* gas_t;
typedef __attribute__((address_space(3))) unsigned int* las_t;

__device__ inline unsigned short f2bf(float f) {
    unsigned int u = __float_as_uint(f);
    u += 0x7FFF + ((u >> 16) & 1);   // RNE
    return (unsigned short)(u >> 16);
}

__device__ __forceinline__ float exp2_fast(float x) {
#if __has_builtin(__builtin_amdgcn_exp2f)
    return __builtin_amdgcn_exp2f(x);
#else
    return exp2f(x);
#endif
}

__device__ __forceinline__ float rcp_fast(float x) {
#if __has_builtin(__builtin_amdgcn_rcpf)
    return __builtin_amdgcn_rcpf(x);
#else
    return 1.0f / x;
#endif
}

// pack two positive floats to bf16x2 (round-half-up), lo in low 16 bits
__device__ __forceinline__ unsigned int pack_bf16x2(float lo, float hi) {
    unsigned int a = __float_as_uint(lo) + 0x8000u;
    unsigned int b = __float_as_uint(hi) + 0x8000u;
#if __has_builtin(__builtin_amdgcn_perm)
    return __builtin_amdgcn_perm(b, a, 0x07060302u);
#else
    return (a >> 16) | (b & 0xFFFF0000u);
#endif
}

// ---------------- fp32 -> bf16 convert (4 elems/thread), both tensors ------
// R8-proven: merged into one dispatch.
__global__ void cvt_bf16_2(const float* __restrict__ a,
                           unsigned short* __restrict__ oa, int n4a,
                           const float* __restrict__ bsrc,
                           unsigned short* __restrict__ ob, int n4b) {
    int i = blockIdx.x * blockDim.x + threadIdx.x;
    if (i < n4a) {
        float4 v = ((const float4*)a)[i];
        ushort4 o;
        o.x = f2bf(v.x); o.y = f2bf(v.y); o.z = f2bf(v.z); o.w = f2bf(v.w);
        ((ushort4*)oa)[i] = o;
    } else {
        int j = i - n4a;
        if (j < n4b) {
            float4 v = ((const float4*)bsrc)[j];
            ushort4 o;
            o.x = f2bf(v.x); o.y = f2bf(v.y); o.z = f2bf(v.z); o.w = f2bf(v.w);
            ((ushort4*)ob)[j] = o;
        }
    }
}

// ---------------- QKV projection GEMM ----------------
// R8-proven 2-phase: global_load_lds staging + XCD swizzle + dbuf +
// chunk-XOR bank swizzle. Untouched.
__global__ __launch_bounds__(256) void qkv_gemm(
    const unsigned short* __restrict__ Xb,
    const unsigned short* __restrict__ Wb,
    unsigned short* __restrict__ Qo,
    unsigned short* __restrict__ Ko,
    unsigned short* __restrict__ Vt)
{
    __shared__ __align__(16) unsigned short As[2 * 128 * 32];
    __shared__ __align__(16) unsigned short Bs[2 * 128 * 32];

    const int t    = threadIdx.x;
    // XCD swizzle: flat in dispatch order (x fastest), 8 XCDs round-robin
    const int flat = blockIdx.y * 24 + blockIdx.x;
    const int sw   = (flat & 7) * 192 + (flat >> 3);
    const int m0   = (sw / 24) * 128;
    const int n0   = (sw % 24) * 128;

    const int wid  = t >> 6;
    const int lane = t & 63;
    const int l15  = lane & 15;
    const int quad = lane >> 4;
    const int wm   = (wid >> 1) * 64;
    const int wn   = (wid & 1) * 64;

    const int rA   = wid * 32 + (lane >> 2);
    const int kcol_phys = (lane & 3) * 8;
    const int kcol_src  = ((lane & 3) ^ ((rA >> 1) & 3)) * 8;
    const unsigned short* gA = &Xb[(size_t)(m0 + rA) * 1024 + kcol_src];
    const unsigned short* gB = &Wb[(size_t)(n0 + rA) * 1024 + kcol_src];

    const int cswq = (quad ^ ((l15 >> 1) & 3)) * 8;

    f32x4 acc[4][4] = {};

    auto stage = [&](int k0, int bufE) {
        #pragma unroll
        for (int rd = 0; rd < 2; rd++) {
            __builtin_amdgcn_global_load_lds(
                (gas_t)(const void*)(gA + rd * 16 * 1024 + k0),
                (las_t)(void*)&As[bufE + (rA + rd * 16) * 32 + kcol_phys], 16, 0, 0);
            __builtin_amdgcn_global_load_lds(
                (gas_t)(const void*)(gB + rd * 16 * 1024 + k0),
                (las_t)(void*)&Bs[bufE + (rA + rd * 16) * 32 + kcol_phys], 16, 0, 0);
        }
    };

    auto comp = [&](int bufE) {
        s16x8 af[4], bf[4];
        #pragma unroll
        for (int mt = 0; mt < 4; mt++)
            af[mt] = *(const s16x8*)&As[bufE + (wm + mt * 16 + l15) * 32 + cswq];
        #pragma unroll
        for (int nt = 0; nt < 4; nt++)
            bf[nt] = *(const s16x8*)&Bs[bufE + (wn + nt * 16 + l15) * 32 + cswq];
        #pragma unroll
        for (int mt = 0; mt < 4; mt++)
            #pragma unroll
            for (int nt = 0; nt < 4; nt++)
                acc[mt][nt] = __builtin_amdgcn_mfma_f32_16x16x32_bf16(
                    af[mt], bf[nt], acc[mt][nt], 0, 0, 0);
    };

    // prologue
    stage(0, 0);
    __syncthreads();

    #pragma unroll 1
    for (int k0 = 0; k0 < 1024; k0 += 64) {
        stage(k0 + 32, 4096);
        comp(0);
        __syncthreads();
        if (k0 + 64 < 1024) stage(k0 + 64, 0);
        comp(4096);
        __syncthreads();
    }

    #pragma unroll
    for (int mt = 0; mt < 4; mt++) {
        const int mbase = m0 + wm + mt * 16 + quad * 4;
        const int b     = mbase >> 11;
        const int nbase = mbase & 2047;
        #pragma unroll
        for (int nt = 0; nt < 4; nt++) {
            const int o  = n0 + wn + nt * 16 + l15;
            const int p  = o >> 10;
            const int oo = o & 1023;
            const int h  = oo >> 6;
            const int d  = oo & 63;
            if (p == 0) {
                #pragma unroll
                for (int r = 0; r < 4; r++)
                    Qo[((size_t)(b * 16 + h) * 2048 + nbase + r) * 64 + d] =
                        f2bf(acc[mt][nt][r] * QSC);
            } else if (p == 1) {
                #pragma unroll
                for (int r = 0; r < 4; r++)
                    Ko[((size_t)(b * 16 + h) * 2048 + nbase + r) * 64 + d] =
                        f2bf(acc[mt][nt][r]);
            } else {
                ushort4 v4;
                v4.x = f2bf(acc[mt][nt][0]);
                v4.y = f2bf(acc[mt][nt][1]);
                v4.z = f2bf(acc[mt][nt][2]);
                v4.w = f2bf(acc[mt][nt][3]);
                *(ushort4*)&Vt[((size_t)(b * 16 + h) * 64 + d) * 2048 + nbase] = v4;
            }
        }
    }
}

// ---------------- fused attention ----------------
// R15 = R12 verbatim (proven best: attn 92.3 us). 8-wave blocks (512 thr),
// 256 q-rows/block, grid (8,64) = 512 blocks = 2/CU -> 16 waves/CU.
// K AND V staged in LDS via global_load_lds (async, double-buffered) —
// V-direct-from-global is a twice-confirmed dead end (R10: vmcnt ordering;
// R14: scattered L2 reads, per-wave V re-read). XOR swizzle for
// conflict-free ds_read_b128; softmax pack_bf16x2; row sums via ones-MFMA;
// shared zero-C for QK^T. No setprio (R8-null).
// LDS map (ushort elems): K0@0, V0@4096, K1@8192, V1@12288, P@16384+w*2304.
#define PSTRIDE 72
#define PBASE   16384

__global__ __launch_bounds__(512) void attn(
    const unsigned short* __restrict__ Q,
    const unsigned short* __restrict__ K,
    const unsigned short* __restrict__ Vt,
    float* __restrict__ out)
{
    __shared__ __align__(16) unsigned short LDS[PBASE + 8 * 32 * PSTRIDE];

    const int t    = threadIdx.x;
    const int w    = t >> 6;                // 0..7
    const int lane = t & 63;
    const int l15  = lane & 15;
    const int quad = lane >> 4;
    const int head = blockIdx.y;            // b*16 + h
    const int b    = head >> 4;
    const int h    = head & 15;
    const int q0   = blockIdx.x * 256 + w * 32;

    const unsigned short* Qh = Q  + (size_t)head * 2048 * 64;
    const unsigned short* Kh = K  + (size_t)head * 2048 * 64;
    const unsigned short* Vh = Vt + (size_t)head * 64 * 2048;

    // ---- staging source addresses (per thread, lane-linear LDS dst) ----
    // phys chunk i = t holds logical (row=i>>3, col=(i&7)^(row&7)); 512
    // threads cover all 64 rows x 8 chunks in one DMA round.
    const int r0 = t >> 3;                    // 0..63
    const int c0 = (t & 7) ^ (r0 & 7);
    const unsigned short* srcK = Kh + r0 * 64 + c0 * 8;
    const unsigned short* srcV = Vh + r0 * 2048 + c0 * 8;

    auto stageKV = [&](int kt, int bufE) {
        __builtin_amdgcn_global_load_lds(
            (gas_t)(const void*)(srcK + kt * 4096),
            (las_t)(void*)&LDS[bufE + t * 8], 16, 0, 0);
        __builtin_amdgcn_global_load_lds(
            (gas_t)(const void*)(srcV + kt * 64),
            (las_t)(void*)&LDS[bufE + 4096 + t * 8], 16, 0, 0);
    };

    // Q fragments (pre-scaled by QSC in gemm), B-operand role
    s16x8 qb[2][2];
    #pragma unroll
    for (int mt = 0; mt < 2; mt++)
        #pragma unroll
        for (int kc = 0; kc < 2; kc++)
            qb[mt][kc] = *(const s16x8*)&Qh[(size_t)(q0 + mt * 16 + l15) * 64 + kc * 32 + quad * 8];

    // ones B-fragment (bf16 1.0) for MFMA row-sums
    s16x8 onesf;
    #pragma unroll
    for (int i = 0; i < 8; i++) onesf[i] = (short)0x3F80;
    const f32x4 fz = {0.f, 0.f, 0.f, 0.f};

    f32x4 y[2][4] = {};
    f32x4 ysum[2] = {};
    unsigned short* P = &LDS[PBASE + w * (32 * PSTRIDE)];

    // swizzled in-tile column offsets (elems) for kc=0/1
    const int x7   = l15 & 7;
    const int csw0 = (quad ^ x7) * 8;
    const int csw1 = ((4 + quad) ^ x7) * 8;

    auto compute = [&](int bufE) {
        // K fragments from LDS
        s16x8 kb[4][2];
        #pragma unroll
        for (int nt = 0; nt < 4; nt++) {
            const int rowb = bufE + (nt * 16 + l15) * 64;
            kb[nt][0] = *(const s16x8*)&LDS[rowb + csw0];
            kb[nt][1] = *(const s16x8*)&LDS[rowb + csw1];
        }
        // S^T = K * Q^T  (kc=0 consumes shared zero C; kc=1 accumulates)
        f32x4 st[4][2];
        #pragma unroll
        for (int nt = 0; nt < 4; nt++)
            #pragma unroll
            for (int mt = 0; mt < 2; mt++)
                st[nt][mt] = __builtin_amdgcn_mfma_f32_16x16x32_bf16(
                    kb[nt][0], qb[mt][0], fz, 0, 0, 0);
        #pragma unroll
        for (int nt = 0; nt < 4; nt++)
            #pragma unroll
            for (int mt = 0; mt < 2; mt++)
                st[nt][mt] = __builtin_amdgcn_mfma_f32_16x16x32_bf16(
                    kb[nt][1], qb[mt][1], st[nt][mt], 0, 0, 0);
        // V fragments from LDS (issued before the exp block)
        s16x8 vb[4][2];
        #pragma unroll
        for (int dt = 0; dt < 4; dt++) {
            const int rowb = bufE + 4096 + (dt * 16 + l15) * 64;
            vb[dt][0] = *(const s16x8*)&LDS[rowb + csw0];
            vb[dt][1] = *(const s16x8*)&LDS[rowb + csw1];
        }
        // exp2 + pack + ds_write_b64 into per-wave P region
        #pragma unroll
        for (int mt = 0; mt < 2; mt++)
            #pragma unroll
            for (int nt = 0; nt < 4; nt++) {
                float p0 = exp2_fast(st[nt][mt][0]);
                float p1 = exp2_fast(st[nt][mt][1]);
                float p2 = exp2_fast(st[nt][mt][2]);
                float p3 = exp2_fast(st[nt][mt][3]);
                uint2 u;
                u.x = pack_bf16x2(p0, p1);
                u.y = pack_bf16x2(p2, p3);
                *(uint2*)&P[(mt * 16 + l15) * PSTRIDE + nt * 16 + quad * 4] = u;
            }
        // Y += P V ; row sums via ones-MFMA (denominator = bf16 P, consistent
        // with the PV numerator)
        #pragma unroll
        for (int kc = 0; kc < 2; kc++) {
            s16x8 pa[2];
            #pragma unroll
            for (int mt = 0; mt < 2; mt++)
                pa[mt] = *(const s16x8*)&P[(mt * 16 + l15) * PSTRIDE + kc * 32 + quad * 8];
            #pragma unroll
            for (int mt = 0; mt < 2; mt++)
                ysum[mt] = __builtin_amdgcn_mfma_f32_16x16x32_bf16(
                    pa[mt], onesf, ysum[mt], 0, 0, 0);
            #pragma unroll
            for (int mt = 0; mt < 2; mt++)
                #pragma unroll
                for (int dt = 0; dt < 4; dt++)
                    y[mt][dt] = __builtin_amdgcn_mfma_f32_16x16x32_bf16(
                        pa[mt], vb[dt][kc], y[mt][dt], 0, 0, 0);
        }
    };

    // -------- prologue --------
    stageKV(0, 0);
    __syncthreads();            // drain (vmcnt 0) + barrier: buf0 ready

    // -------- main loop: issue next (other buffer) -> compute -> barrier ----
    #pragma unroll 1
    for (int kt = 0; kt < 32; kt += 2) {
        stageKV(kt + 1, 8192);          // kt+1 <= 31 always
        compute(0);
        __syncthreads();
        if (kt + 2 < 32) stageKV(kt + 2, 0);
        compute(8192);
        __syncthreads();
    }

    // ysum[mt][r] holds the full row sum for q-row = mt*16 + quad*4 + r
    float rinv[2][4];
    #pragma unroll
    for (int mt = 0; mt < 2; mt++)
        #pragma unroll
        for (int r = 0; r < 4; r++)
            rinv[mt][r] = rcp_fast(ysum[mt][r]);

    // out[b, n, h*64+d] fp32; C-layout: col=l15 -> d, row=quad*4+r -> m
    #pragma unroll
    for (int mt = 0; mt < 2; mt++)
        #pragma unroll
        for (int dt = 0; dt < 4; dt++)
            #pragma unroll
            for (int r = 0; r < 4; r++) {
                const int n = q0 + mt * 16 + quad * 4 + r;
                const int d = dt * 16 + l15;
                out[((size_t)(b * 2048 + n)) * 1024 + h * 64 + d] =
                    y[mt][dt][r] * rinv[mt][r];
            }
}

// ---------------- launch ----------------
extern "C" void kernel_launch(void* const* d_in, const int* in_sizes, int n_in,
                              void* d_out, int out_size, void* d_ws, size_t ws_size,
                              hipStream_t stream) {
    const float* X = (const float*)d_in[0];   // [4,2048,1024]
    const float* W = (const float*)d_in[1];   // [3072,1024]
    float* out = (float*)d_out;

    char* ws = (char*)d_ws;
    unsigned short* Xb = (unsigned short*)(ws);                 // 16.8 MB
    unsigned short* Wb = (unsigned short*)(ws + 16777216);      //  6.3 MB
    unsigned short* Qb = (unsigned short*)(ws + 23068672);      // 16.8 MB
    unsigned short* Kb = (unsigned short*)(ws + 39845888);      // 16.8 MB
    unsigned short* Vt = (unsigned short*)(ws + 56623104);      // 16.8 MB (ends 73.4 MB)

    cvt_bf16_2<<<dim3(11264), dim3(256), 0, stream>>>(X, Xb, 2097152, W, Wb, 786432);
    qkv_gemm<<<dim3(24, 64), dim3(256), 0, stream>>>(Xb, Wb, Qb, Kb, Vt);
    attn<<<dim3(8, 64), dim3(512), 0, stream>>>(Qb, Kb, Vt, out);
}

// Round 16
// 227.209 us; speedup vs baseline: 2.0347x; 1.0696x over previous
//
#include <hip/hip_runtime.h>

// Problem constants
#define BATCH   4
#define SEQ     2048
#define DMODEL  1024
#define NHEADS  16
#define HDIM    64
// SCALE * log2(e) folded into Q at the GEMM epilogue: exp(s*0.125) = exp2(s*QSC)
#define QSC     0.18033688f

typedef short s16x8 __attribute__((ext_vector_type(8)));
typedef float f32x4 __attribute__((ext_vector_type(4)));
typedef const __attribute__((address_space(1))) unsigned int* gas_t;
typedef __attribute__((address_space(3))) unsigned int* las_t;

__device__ inline unsigned short f2bf(float f) {
    unsigned int u = __float_as_uint(f);
    u += 0x7FFF + ((u >> 16) & 1);   // RNE
    return (unsigned short)(u >> 16);
}

__device__ __forceinline__ float exp2_fast(float x) {
#if __has_builtin(__builtin_amdgcn_exp2f)
    return __builtin_amdgcn_exp2f(x);
#else
    return exp2f(x);
#endif
}

__device__ __forceinline__ float rcp_fast(float x) {
#if __has_builtin(__builtin_amdgcn_rcpf)
    return __builtin_amdgcn_rcpf(x);
#else
    return 1.0f / x;
#endif
}

// pack two positive floats to bf16x2 (round-half-up), lo in low 16 bits
__device__ __forceinline__ unsigned int pack_bf16x2(float lo, float hi) {
    unsigned int a = __float_as_uint(lo) + 0x8000u;
    unsigned int b = __float_as_uint(hi) + 0x8000u;
#if __has_builtin(__builtin_amdgcn_perm)
    return __builtin_amdgcn_perm(b, a, 0x07060302u);
#else
    return (a >> 16) | (b & 0xFFFF0000u);
#endif
}

// ---------------- fp32 -> bf16 convert (4 elems/thread), both tensors ------
// R8-proven: merged into one dispatch.
__global__ void cvt_bf16_2(const float* __restrict__ a,
                           unsigned short* __restrict__ oa, int n4a,
                           const float* __restrict__ bsrc,
                           unsigned short* __restrict__ ob, int n4b) {
    int i = blockIdx.x * blockDim.x + threadIdx.x;
    if (i < n4a) {
        float4 v = ((const float4*)a)[i];
        ushort4 o;
        o.x = f2bf(v.x); o.y = f2bf(v.y); o.z = f2bf(v.z); o.w = f2bf(v.w);
        ((ushort4*)oa)[i] = o;
    } else {
        int j = i - n4a;
        if (j < n4b) {
            float4 v = ((const float4*)bsrc)[j];
            ushort4 o;
            o.x = f2bf(v.x); o.y = f2bf(v.y); o.z = f2bf(v.z); o.w = f2bf(v.w);
            ((ushort4*)ob)[j] = o;
        }
    }
}

// ---------------- QKV projection GEMM ----------------
// R16: 256x192 tile, 8 waves (2M x 4N), per-wave 128x48 output (acc[8][3]).
// Rationale: qkv is LDS-pipe-bound (reads/MFMA + staged-write traffic), so
// the levers are per-wave fragment reuse and tile area: staged traffic
// 806 -> 470 MB; 512 blocks = EXACTLY 2.0 rounds at 1 block/CU (no tail).
// Fine-phase schedule (m201 regime: 1 block/CU, schedule-driven overlap):
// per K-tile (BK=32) 2 phases {ds_read frags; stage half of T+1; s_barrier;
// setprio(1); 12 MFMA; setprio(0); s_barrier}, tile-end __syncthreads
// (vmcnt-0 drain lands >=1 phase after issue). Race ledger = R8-dbuf
// invariant. K-order unchanged -> bit-identical output (absmax canary).
// Chunk-XOR swizzle (R7-proven): conflict-free ds_read_b128.
__global__ __launch_bounds__(512) void qkv_gemm(
    const unsigned short* __restrict__ Xb,
    const unsigned short* __restrict__ Wb,
    unsigned short* __restrict__ Qo,
    unsigned short* __restrict__ Ko,
    unsigned short* __restrict__ Vt)
{
    __shared__ __align__(16) unsigned short As[2 * 8192];   // 256 x 32 per buf
    __shared__ __align__(16) unsigned short Bs[2 * 6144];   // 192 x 32 per buf

    const int t    = threadIdx.x;
    // XCD swizzle: 512 blocks, 64/XCD, bijective
    const int flat = blockIdx.y * 16 + blockIdx.x;
    const int sw   = (flat & 7) * 64 + (flat >> 3);
    const int m0   = (sw >> 4) * 256;
    const int n0   = (sw & 15) * 192;

    const int wid  = t >> 6;
    const int lane = t & 63;
    const int l15  = lane & 15;
    const int quad = lane >> 4;
    const int wr   = wid >> 2;      // 0..1: M-row of wave
    const int wc   = wid & 3;       // 0..3: N-col of wave

    // staging source (per thread): row = g*128 + (t>>2), pre-swizzled chunk
    const int srow = t >> 2;                                   // 0..127
    const int csrc = ((t & 3) ^ ((t >> 3) & 3)) * 8;           // g-invariant
    const unsigned short* gA = &Xb[(size_t)(m0 + srow) * 1024 + csrc];
    const unsigned short* gB = &Wb[(size_t)(n0 + srow) * 1024 + csrc];

    // swizzled fragment read chunk (R7-proven): phys = quad ^ ((l15>>1)&3)
    const int cswq = (quad ^ ((l15 >> 1) & 3)) * 8;

    const int arow = wr * 128 + l15;    // + mr*16
    const int brow = wc * 48 + l15;     // + nr*16

    f32x4 acc[8][3] = {};

    auto stageA = [&](int k0, int bufE) {
        #pragma unroll
        for (int g = 0; g < 2; g++)
            __builtin_amdgcn_global_load_lds(
                (gas_t)(const void*)(gA + (size_t)g * 131072 + k0),
                (las_t)(void*)&As[bufE + (g * 512 + t) * 8], 16, 0, 0);
    };
    auto stageB = [&](int k0, int bufE) {
        __builtin_amdgcn_global_load_lds(
            (gas_t)(const void*)(gB + k0),
            (las_t)(void*)&Bs[bufE + t * 8], 16, 0, 0);
        if (wid < 4)    // rows 128..191: 256 threads (4 waves), wave-uniform
            __builtin_amdgcn_global_load_lds(
                (gas_t)(const void*)(gB + (size_t)131072 + k0),
                (las_t)(void*)&Bs[bufE + (512 + t) * 8], 16, 0, 0);
    };

    // -------- prologue: stage tile 0 --------
    stageA(0, 0);
    stageB(0, 0);
    __syncthreads();

    #pragma unroll 1
    for (int T = 0; T < 32; T++) {
        const int bufA = (T & 1) * 8192;
        const int bufB = (T & 1) * 6144;
        const int oA   = 8192 - bufA;
        const int oB   = 6144 - bufB;
        const int kn   = (T + 1) * 32;

        s16x8 bfr[3];
        // ---- phase 0: mr 0..3 ----
        {
            s16x8 afr[4];
            #pragma unroll
            for (int mr = 0; mr < 4; mr++)
                afr[mr] = *(const s16x8*)&As[bufA + (arow + mr * 16) * 32 + cswq];
            #pragma unroll
            for (int nr = 0; nr < 3; nr++)
                bfr[nr] = *(const s16x8*)&Bs[bufB + (brow + nr * 16) * 32 + cswq];
            if (T < 31) stageA(kn, oA);
            __builtin_amdgcn_s_barrier();
            __builtin_amdgcn_s_setprio(1);
            #pragma unroll
            for (int mr = 0; mr < 4; mr++)
                #pragma unroll
                for (int nr = 0; nr < 3; nr++)
                    acc[mr][nr] = __builtin_amdgcn_mfma_f32_16x16x32_bf16(
                        afr[mr], bfr[nr], acc[mr][nr], 0, 0, 0);
            __builtin_amdgcn_s_setprio(0);
            __builtin_amdgcn_s_barrier();
        }
        // ---- phase 1: mr 4..7 (bfr reused) ----
        {
            s16x8 afr[4];
            #pragma unroll
            for (int mr = 0; mr < 4; mr++)
                afr[mr] = *(const s16x8*)&As[bufA + (arow + (4 + mr) * 16) * 32 + cswq];
            if (T < 31) stageB(kn, oB);
            __builtin_amdgcn_s_barrier();
            __builtin_amdgcn_s_setprio(1);
            #pragma unroll
            for (int mr = 0; mr < 4; mr++)
                #pragma unroll
                for (int nr = 0; nr < 3; nr++)
                    acc[4 + mr][nr] = __builtin_amdgcn_mfma_f32_16x16x32_bf16(
                        afr[mr], bfr[nr], acc[4 + mr][nr], 0, 0, 0);
            __builtin_amdgcn_s_setprio(0);
            __syncthreads();   // tile T done; drains T+1's staging DMA
        }
    }

    // -------- epilogue: split C into Q (scaled), K, V^T --------
    #pragma unroll
    for (int mrep = 0; mrep < 8; mrep++) {
        const int mbase = m0 + wr * 128 + mrep * 16 + quad * 4;
        const int b     = mbase >> 11;
        const int nbase = mbase & 2047;
        #pragma unroll
        for (int nrep = 0; nrep < 3; nrep++) {
            const int o  = n0 + wc * 48 + nrep * 16 + l15;
            const int p  = o >> 10;
            const int oo = o & 1023;
            const int h  = oo >> 6;
            const int d  = oo & 63;
            if (p == 0) {
                #pragma unroll
                for (int r = 0; r < 4; r++)
                    Qo[((size_t)(b * 16 + h) * 2048 + nbase + r) * 64 + d] =
                        f2bf(acc[mrep][nrep][r] * QSC);
            } else if (p == 1) {
                #pragma unroll
                for (int r = 0; r < 4; r++)
                    Ko[((size_t)(b * 16 + h) * 2048 + nbase + r) * 64 + d] =
                        f2bf(acc[mrep][nrep][r]);
            } else {
                ushort4 v4;
                v4.x = f2bf(acc[mrep][nrep][0]);
                v4.y = f2bf(acc[mrep][nrep][1]);
                v4.z = f2bf(acc[mrep][nrep][2]);
                v4.w = f2bf(acc[mrep][nrep][3]);
                *(ushort4*)&Vt[((size_t)(b * 16 + h) * 64 + d) * 2048 + nbase] = v4;
            }
        }
    }
}

// ---------------- fused attention ----------------
// R12/R15-proven (attn 92 us): 8-wave blocks, 256 q-rows/block, K+V staged
// in LDS via global_load_lds (dbuf), XOR swizzle, pack_bf16x2 softmax,
// ones-MFMA row sums, shared zero-C. Untouched.
#define PSTRIDE 72
#define PBASE   16384

__global__ __launch_bounds__(512) void attn(
    const unsigned short* __restrict__ Q,
    const unsigned short* __restrict__ K,
    const unsigned short* __restrict__ Vt,
    float* __restrict__ out)
{
    __shared__ __align__(16) unsigned short LDS[PBASE + 8 * 32 * PSTRIDE];

    const int t    = threadIdx.x;
    const int w    = t >> 6;                // 0..7
    const int lane = t & 63;
    const int l15  = lane & 15;
    const int quad = lane >> 4;
    const int head = blockIdx.y;            // b*16 + h
    const int b    = head >> 4;
    const int h    = head & 15;
    const int q0   = blockIdx.x * 256 + w * 32;

    const unsigned short* Qh = Q  + (size_t)head * 2048 * 64;
    const unsigned short* Kh = K  + (size_t)head * 2048 * 64;
    const unsigned short* Vh = Vt + (size_t)head * 64 * 2048;

    const int r0 = t >> 3;                    // 0..63
    const int c0 = (t & 7) ^ (r0 & 7);
    const unsigned short* srcK = Kh + r0 * 64 + c0 * 8;
    const unsigned short* srcV = Vh + r0 * 2048 + c0 * 8;

    auto stageKV = [&](int kt, int bufE) {
        __builtin_amdgcn_global_load_lds(
            (gas_t)(const void*)(srcK + kt * 4096),
            (las_t)(void*)&LDS[bufE + t * 8], 16, 0, 0);
        __builtin_amdgcn_global_load_lds(
            (gas_t)(const void*)(srcV + kt * 64),
            (las_t)(void*)&LDS[bufE + 4096 + t * 8], 16, 0, 0);
    };

    // Q fragments (pre-scaled by QSC in gemm), B-operand role
    s16x8 qb[2][2];
    #pragma unroll
    for (int mt = 0; mt < 2; mt++)
        #pragma unroll
        for (int kc = 0; kc < 2; kc++)
            qb[mt][kc] = *(const s16x8*)&Qh[(size_t)(q0 + mt * 16 + l15) * 64 + kc * 32 + quad * 8];

    // ones B-fragment (bf16 1.0) for MFMA row-sums
    s16x8 onesf;
    #pragma unroll
    for (int i = 0; i < 8; i++) onesf[i] = (short)0x3F80;
    const f32x4 fz = {0.f, 0.f, 0.f, 0.f};

    f32x4 y[2][4] = {};
    f32x4 ysum[2] = {};
    unsigned short* P = &LDS[PBASE + w * (32 * PSTRIDE)];

    const int x7   = l15 & 7;
    const int csw0 = (quad ^ x7) * 8;
    const int csw1 = ((4 + quad) ^ x7) * 8;

    auto compute = [&](int bufE) {
        s16x8 kb[4][2];
        #pragma unroll
        for (int nt = 0; nt < 4; nt++) {
            const int rowb = bufE + (nt * 16 + l15) * 64;
            kb[nt][0] = *(const s16x8*)&LDS[rowb + csw0];
            kb[nt][1] = *(const s16x8*)&LDS[rowb + csw1];
        }
        f32x4 st[4][2];
        #pragma unroll
        for (int nt = 0; nt < 4; nt++)
            #pragma unroll
            for (int mt = 0; mt < 2; mt++)
                st[nt][mt] = __builtin_amdgcn_mfma_f32_16x16x32_bf16(
                    kb[nt][0], qb[mt][0], fz, 0, 0, 0);
        #pragma unroll
        for (int nt = 0; nt < 4; nt++)
            #pragma unroll
            for (int mt = 0; mt < 2; mt++)
                st[nt][mt] = __builtin_amdgcn_mfma_f32_16x16x32_bf16(
                    kb[nt][1], qb[mt][1], st[nt][mt], 0, 0, 0);
        s16x8 vb[4][2];
        #pragma unroll
        for (int dt = 0; dt < 4; dt++) {
            const int rowb = bufE + 4096 + (dt * 16 + l15) * 64;
            vb[dt][0] = *(const s16x8*)&LDS[rowb + csw0];
            vb[dt][1] = *(const s16x8*)&LDS[rowb + csw1];
        }
        #pragma unroll
        for (int mt = 0; mt < 2; mt++)
            #pragma unroll
            for (int nt = 0; nt < 4; nt++) {
                float p0 = exp2_fast(st[nt][mt][0]);
                float p1 = exp2_fast(st[nt][mt][1]);
                float p2 = exp2_fast(st[nt][mt][2]);
                float p3 = exp2_fast(st[nt][mt][3]);
                uint2 u;
                u.x = pack_bf16x2(p0, p1);
                u.y = pack_bf16x2(p2, p3);
                *(uint2*)&P[(mt * 16 + l15) * PSTRIDE + nt * 16 + quad * 4] = u;
            }
        #pragma unroll
        for (int kc = 0; kc < 2; kc++) {
            s16x8 pa[2];
            #pragma unroll
            for (int mt = 0; mt < 2; mt++)
                pa[mt] = *(const s16x8*)&P[(mt * 16 + l15) * PSTRIDE + kc * 32 + quad * 8];
            #pragma unroll
            for (int mt = 0; mt < 2; mt++)
                ysum[mt] = __builtin_amdgcn_mfma_f32_16x16x32_bf16(
                    pa[mt], onesf, ysum[mt], 0, 0, 0);
            #pragma unroll
            for (int mt = 0; mt < 2; mt++)
                #pragma unroll
                for (int dt = 0; dt < 4; dt++)
                    y[mt][dt] = __builtin_amdgcn_mfma_f32_16x16x32_bf16(
                        pa[mt], vb[dt][kc], y[mt][dt], 0, 0, 0);
        }
    };

    // -------- prologue --------
    stageKV(0, 0);
    __syncthreads();

    // -------- main loop --------
    #pragma unroll 1
    for (int kt = 0; kt < 32; kt += 2) {
        stageKV(kt + 1, 8192);
        compute(0);
        __syncthreads();
        if (kt + 2 < 32) stageKV(kt + 2, 0);
        compute(8192);
        __syncthreads();
    }

    float rinv[2][4];
    #pragma unroll
    for (int mt = 0; mt < 2; mt++)
        #pragma unroll
        for (int r = 0; r < 4; r++)
            rinv[mt][r] = rcp_fast(ysum[mt][r]);

    #pragma unroll
    for (int mt = 0; mt < 2; mt++)
        #pragma unroll
        for (int dt = 0; dt < 4; dt++)
            #pragma unroll
            for (int r = 0; r < 4; r++) {
                const int n = q0 + mt * 16 + quad * 4 + r;
                const int d = dt * 16 + l15;
                out[((size_t)(b * 2048 + n)) * 1024 + h * 64 + d] =
                    y[mt][dt][r] * rinv[mt][r];
            }
}

// ---------------- launch ----------------
extern "C" void kernel_launch(void* const* d_in, const int* in_sizes, int n_in,
                              void* d_out, int out_size, void* d_ws, size_t ws_size,
                              hipStream_t stream) {
    const float* X = (const float*)d_in[0];   // [4,2048,1024]
    const float* W = (const float*)d_in[1];   // [3072,1024]
    float* out = (float*)d_out;

    char* ws = (char*)d_ws;
    unsigned short* Xb = (unsigned short*)(ws);                 // 16.8 MB
    unsigned short* Wb = (unsigned short*)(ws + 16777216);      //  6.3 MB
    unsigned short* Qb = (unsigned short*)(ws + 23068672);      // 16.8 MB
    unsigned short* Kb = (unsigned short*)(ws + 39845888);      // 16.8 MB
    unsigned short* Vt = (unsigned short*)(ws + 56623104);      // 16.8 MB (ends 73.4 MB)

    cvt_bf16_2<<<dim3(11264), dim3(256), 0, stream>>>(X, Xb, 2097152, W, Wb, 786432);
    qkv_gemm<<<dim3(16, 32), dim3(512), 0, stream>>>(Xb, Wb, Qb, Kb, Vt);
    attn<<<dim3(8, 64), dim3(512), 0, stream>>>(Qb, Kb, Vt, out);
}